// Round 2
// baseline (259.722 us; speedup 1.0000x reference)
//
#include <hip/hip_runtime.h>

// Problem constants (match reference)
#define BB   8
#define CC   64
#define HH   256
#define WW   512
#define BND  64   // BOUNDARY, direction 'lr'

typedef float f32x4 __attribute__((ext_vector_type(4)));

// Each thread handles 4 consecutive x positions of one (b,c,y) row.
// total threads = B*C*H*(W/4) = 8*64*256*128 = 16,777,216
__global__ __launch_bounds__(256) void warp_feature_kernel(
    const float* __restrict__ disp,      // (B,1,H,W)
    const float* __restrict__ tgt,       // (B,C,H,W)
    float* __restrict__ warped,          // (B,C,H,W)
    float* __restrict__ maskout)         // (B,C,H,W) as 0.0/1.0
{
    const int tid = blockIdx.x * blockDim.x + threadIdx.x;

    const int xq = tid & (WW / 4 - 1);   // 0..127
    int t = tid >> 7;                    // / (W/4)
    const int y = t & (HH - 1);          // 0..255
    t >>= 8;
    const int c = t & (CC - 1);
    const int b = t >> 6;

    const int xbase = xq * 4;

    // ---- iy: depends only on y (reference arithmetic, fp32) ----
    const float shifty = (float)(HH - 1) * 0.5f;                 // 127.5
    const float gy = ((float)y - shifty) / shifty;
    const float iy = ((gy + 1.0f) * (float)HH - 1.0f) * 0.5f;
    const float y0f = floorf(iy);
    const float fy  = iy - y0f;
    const int   y0  = (int)y0f;
    const int   y1  = y0 + 1;
    const float vy0 = (y0 >= 0 && y0 <= HH - 1) ? 1.0f : 0.0f;
    const float vy1 = (y1 >= 0 && y1 <= HH - 1) ? 1.0f : 0.0f;
    const int   y0c = min(max(y0, 0), HH - 1);
    const int   y1c = min(max(y1, 0), HH - 1);

    // disp for 4 pixels (coalesced float4)
    const f32x4 dv = *reinterpret_cast<const f32x4*>(
        disp + ((size_t)b * HH + y) * WW + xbase);

    const float* img  = tgt + (size_t)(b * CC + c) * (HH * WW);
    const float* row0 = img + (size_t)y0c * WW;
    const float* row1 = img + (size_t)y1c * WW;

    const float shiftx = (float)(WW - 1) * 0.5f;                 // 255.5

    f32x4 res;
#pragma unroll
    for (int k = 0; k < 4; ++k) {
        const float X  = (float)(xbase + k);
        const float Xs = X + dv[k];                              // 'lr': X + disp
        const float gx = (Xs - shiftx) / shiftx;
        const float ix = ((gx + 1.0f) * (float)WW - 1.0f) * 0.5f;
        const float x0f = floorf(ix);
        const float fx  = ix - x0f;
        const int   x0  = (int)x0f;
        const int   x1  = x0 + 1;
        const float vx0 = (x0 >= 0 && x0 <= WW - 1) ? 1.0f : 0.0f;
        const float vx1 = (x1 >= 0 && x1 <= WW - 1) ? 1.0f : 0.0f;
        const int   x0c = min(max(x0, 0), WW - 1);
        const int   x1c = min(max(x1, 0), WW - 1);

        const float w00 = (1.0f - fx) * (1.0f - fy) * vx0 * vy0;
        const float w10 = fx          * (1.0f - fy) * vx1 * vy0;
        const float w01 = (1.0f - fx) * fy          * vx0 * vy1;
        const float w11 = fx          * fy          * vx1 * vy1;

        float v = row0[x0c] * w00;
        v = fmaf(row0[x1c], w10, v);
        v = fmaf(row1[x0c], w01, v);
        v = fmaf(row1[x1c], w11, v);
        res[k] = v;
    }

    const size_t obase = ((size_t)(b * CC + c) * HH + y) * WW + xbase;

    __builtin_nontemporal_store(res, reinterpret_cast<f32x4*>(warped + obase));

    // mask: x < W - BOUNDARY (448). xbase is a multiple of 4, 448 % 4 == 0,
    // so the whole quad is uniform.
    const float mval = (xbase < (WW - BND)) ? 1.0f : 0.0f;
    f32x4 mv = { mval, mval, mval, mval };
    __builtin_nontemporal_store(mv, reinterpret_cast<f32x4*>(maskout + obase));
}

extern "C" void kernel_launch(void* const* d_in, const int* in_sizes, int n_in,
                              void* d_out, int out_size, void* d_ws, size_t ws_size,
                              hipStream_t stream) {
    const float* disp = (const float*)d_in[0];
    const float* tgt  = (const float*)d_in[1];
    float* warped  = (float*)d_out;
    float* maskout = (float*)d_out + (size_t)BB * CC * HH * WW;

    const int total_threads = BB * CC * HH * (WW / 4);   // 16,777,216
    const int block = 256;
    const int grid  = total_threads / block;             // 65,536

    hipLaunchKernelGGL(warp_feature_kernel, dim3(grid), dim3(block), 0, stream,
                       disp, tgt, warped, maskout);
}

// Round 3
// 139.530 us; speedup vs baseline: 1.8614x; 1.8614x over previous
//
#include <hip/hip_runtime.h>

// Problem constants (match reference)
#define BB   8
#define CC   64
#define HH   256
#define WW   512
#define BND  64   // BOUNDARY, direction 'lr'

typedef float f32x2 __attribute__((ext_vector_type(2)));
typedef float f32x4 __attribute__((ext_vector_type(4)));

// One block per (b,c,y) output row. Stage the two source rows in LDS with
// coalesced float4 loads; each thread interpolates 2 adjacent pixels.
// grid = B*C*H = 131072 blocks of 256 threads.
__global__ __launch_bounds__(256) void warp_feature_kernel(
    const float* __restrict__ disp,      // (B,1,H,W)
    const float* __restrict__ tgt,       // (B,C,H,W)
    float* __restrict__ warped,          // (B,C,H,W)
    float* __restrict__ maskout)         // (B,C,H,W) as 0.0/1.0
{
    __shared__ float rows[2][WW];        // 4 KB

    // XCD-aware bijective swizzle: 131072 % 8 == 0, chunk = 16384 blocks.
    // Keeps adjacent-y blocks (which share a tgt row) on the same XCD L2.
    const int nwg   = BB * CC * HH;
    const int chunk = nwg / 8;
    const int bid0  = blockIdx.x;
    const int bid   = (bid0 % 8) * chunk + (bid0 / 8);

    const int y  = bid & (HH - 1);
    const int bc = bid >> 8;             // b*CC + c
    const int b  = bc >> 6;
    const int t  = threadIdx.x;

    // ---- y geometry (uniform per block; reference arithmetic, fp32) ----
    const float shifty = 127.5f;
    const float gy  = ((float)y - shifty) / shifty;
    const float iy  = ((gy + 1.0f) * (float)HH - 1.0f) * 0.5f;
    const float y0f = floorf(iy);
    const float fy  = iy - y0f;
    const int   y0  = (int)y0f;
    const int   y1  = y0 + 1;
    const float vy0 = (y0 >= 0 && y0 <= HH - 1) ? 1.0f : 0.0f;
    const float vy1 = (y1 >= 0 && y1 <= HH - 1) ? 1.0f : 0.0f;
    const int   y0c = min(max(y0, 0), HH - 1);
    const int   y1c = min(max(y1, 0), HH - 1);

    const float* img = tgt + (size_t)bc * (HH * WW);

    // ---- stage rows y0c (threads 0-127) and y1c (threads 128-255) ----
    {
        const int r    = t >> 7;                 // 0 or 1
        const int xi   = (t & 127) * 4;
        const int ysel = r ? y1c : y0c;
        const f32x4 v  = *reinterpret_cast<const f32x4*>(img + (size_t)ysel * WW + xi);
        *reinterpret_cast<f32x4*>(&rows[r][xi]) = v;
    }
    __syncthreads();

    // ---- each thread: 2 adjacent pixels ----
    const int xpx = t * 2;
    const f32x2 dv = *reinterpret_cast<const f32x2*>(
        disp + ((size_t)b * HH + y) * WW + xpx);

    const float shiftx = 255.5f;
    const float oneMfy = 1.0f - fy;

    f32x2 res;
#pragma unroll
    for (int k = 0; k < 2; ++k) {
        const float X   = (float)(xpx + k);
        const float Xs  = X + dv[k];                         // 'lr': X + disp
        const float gx  = (Xs - shiftx) / shiftx;
        const float ix  = ((gx + 1.0f) * (float)WW - 1.0f) * 0.5f;
        const float x0f = floorf(ix);
        const float fx  = ix - x0f;
        const int   x0  = (int)x0f;
        const int   x1  = x0 + 1;
        const float vx0 = (x0 >= 0 && x0 <= WW - 1) ? 1.0f : 0.0f;
        const float vx1 = (x1 >= 0 && x1 <= WW - 1) ? 1.0f : 0.0f;
        const int   x0c = min(max(x0, 0), WW - 1);
        const int   x1c = min(max(x1, 0), WW - 1);

        const float w00 = (1.0f - fx) * oneMfy * vx0 * vy0;
        const float w10 = fx          * oneMfy * vx1 * vy0;
        const float w01 = (1.0f - fx) * fy     * vx0 * vy1;
        const float w11 = fx          * fy     * vx1 * vy1;

        float v = rows[0][x0c] * w00;            // ds_read2-mergeable pairs
        v = fmaf(rows[0][x1c], w10, v);
        v = fmaf(rows[1][x0c], w01, v);
        v = fmaf(rows[1][x1c], w11, v);
        res[k] = v;
    }

    const size_t obase = ((size_t)bc * HH + y) * WW + xpx;
    __builtin_nontemporal_store(res, reinterpret_cast<f32x2*>(warped + obase));

    // mask: x < 448; xpx even, 448 even -> pair-uniform
    const float mval = (xpx < (WW - BND)) ? 1.0f : 0.0f;
    f32x2 mv = { mval, mval };
    __builtin_nontemporal_store(mv, reinterpret_cast<f32x2*>(maskout + obase));
}

extern "C" void kernel_launch(void* const* d_in, const int* in_sizes, int n_in,
                              void* d_out, int out_size, void* d_ws, size_t ws_size,
                              hipStream_t stream) {
    const float* disp = (const float*)d_in[0];
    const float* tgt  = (const float*)d_in[1];
    float* warped  = (float*)d_out;
    float* maskout = (float*)d_out + (size_t)BB * CC * HH * WW;

    const int grid = BB * CC * HH;               // 131072
    hipLaunchKernelGGL(warp_feature_kernel, dim3(grid), dim3(256), 0, stream,
                       disp, tgt, warped, maskout);
}

// Round 4
// 127.005 us; speedup vs baseline: 2.0450x; 1.0986x over previous
//
#include <hip/hip_runtime.h>

// Problem constants (match reference)
#define BB   8
#define CC   64
#define HH   256
#define WW   512
#define BND  64   // BOUNDARY, direction 'lr'

typedef float f32x4 __attribute__((ext_vector_type(4)));

// One block per (b,c, y-pair). Stage the up-to-4 source rows in LDS with
// coalesced float4 loads; each half-block (2 waves) handles one output row,
// 4 px/thread, dwordx4 NT stores for both outputs.
// grid = B*C*H/2 = 65536 blocks of 256 threads.
__global__ __launch_bounds__(256) void warp_feature_kernel(
    const float* __restrict__ disp,      // (B,1,H,W)
    const float* __restrict__ tgt,       // (B,C,H,W)
    float* __restrict__ warped,          // (B,C,H,W)
    float* __restrict__ maskout)         // (B,C,H,W) as 0.0/1.0
{
    __shared__ float rows[4][WW];        // 8 KB

    // XCD-aware bijective swizzle: 65536 % 8 == 0, chunk = 8192 blocks.
    const int nwg   = BB * CC * (HH / 2);
    const int chunk = nwg / 8;
    const int bid0  = blockIdx.x;
    const int bid   = (bid0 % 8) * chunk + (bid0 / 8);

    const int yq    = bid & (HH / 2 - 1);
    const int ybase = yq * 2;
    const int bc    = bid >> 7;          // b*CC + c
    const int b     = bc >> 6;
    const int t     = threadIdx.x;

    // ---- y geometry for both rows (reference arithmetic, fp32) ----
    const float shifty = 127.5f;
    float fyr[2]; int y0cr[2], y1cr[2]; float vy0r[2], vy1r[2];
#pragma unroll
    for (int r = 0; r < 2; ++r) {
        const float yy  = (float)(ybase + r);
        const float gy  = (yy - shifty) / shifty;
        const float iy  = ((gy + 1.0f) * (float)HH - 1.0f) * 0.5f;
        const float y0f = floorf(iy);
        fyr[r]  = iy - y0f;
        const int y0 = (int)y0f;
        const int y1 = y0 + 1;
        vy0r[r] = (y0 >= 0 && y0 <= HH - 1) ? 1.0f : 0.0f;
        vy1r[r] = (y1 >= 0 && y1 <= HH - 1) ? 1.0f : 0.0f;
        y0cr[r] = min(max(y0, 0), HH - 1);
        y1cr[r] = min(max(y1, 0), HH - 1);
    }

    const float* img = tgt + (size_t)bc * (HH * WW);

    // ---- stage 4 rows: slot0=y0c(ya) slot1=y1c(ya) slot2=y0c(yb) slot3=y1c(yb)
    const int u7  = t >> 7;              // 0 or 1 (wave-uniform)
    const int pos = (t & 127) * 4;
    {
        const int ysel0 = u7 ? y1cr[0] : y0cr[0];
        const int ysel1 = u7 ? y1cr[1] : y0cr[1];
        const f32x4 v0 = *reinterpret_cast<const f32x4*>(img + (size_t)ysel0 * WW + pos);
        const f32x4 v1 = *reinterpret_cast<const f32x4*>(img + (size_t)ysel1 * WW + pos);
        *reinterpret_cast<f32x4*>(&rows[u7][pos])     = v0;
        *reinterpret_cast<f32x4*>(&rows[2 + u7][pos]) = v1;
    }
    __syncthreads();

    // ---- each half-block computes one output row, 4 px/thread ----
    const int  half = u7;
    const int  y    = ybase + half;
    const float fy  = half ? fyr[1] : fyr[0];
    const float vy0 = half ? vy0r[1] : vy0r[0];
    const float vy1 = half ? vy1r[1] : vy1r[0];
    const float oneMfy = 1.0f - fy;
    const float* rowlo = &rows[half * 2][0];
    const float* rowhi = &rows[half * 2 + 1][0];

    const int xpx = (t & 127) * 4;
    const f32x4 dv = *reinterpret_cast<const f32x4*>(
        disp + ((size_t)b * HH + y) * WW + xpx);

    const float shiftx = 255.5f;

    f32x4 res;
#pragma unroll
    for (int k = 0; k < 4; ++k) {
        const float X   = (float)(xpx + k);
        const float Xs  = X + dv[k];                         // 'lr': X + disp
        const float gx  = (Xs - shiftx) / shiftx;
        const float ix  = ((gx + 1.0f) * (float)WW - 1.0f) * 0.5f;
        const float x0f = floorf(ix);
        const float fx  = ix - x0f;
        const int   x0  = (int)x0f;
        const int   x1  = x0 + 1;
        const float vx0 = (x0 >= 0 && x0 <= WW - 1) ? 1.0f : 0.0f;
        const float vx1 = (x1 >= 0 && x1 <= WW - 1) ? 1.0f : 0.0f;
        const int   x0c = min(max(x0, 0), WW - 1);
        const int   x1c = min(max(x1, 0), WW - 1);

        const float w00 = (1.0f - fx) * oneMfy * vx0 * vy0;
        const float w10 = fx          * oneMfy * vx1 * vy0;
        const float w01 = (1.0f - fx) * fy     * vx0 * vy1;
        const float w11 = fx          * fy     * vx1 * vy1;

        float v = rowlo[x0c] * w00;
        v = fmaf(rowlo[x1c], w10, v);
        v = fmaf(rowhi[x0c], w01, v);
        v = fmaf(rowhi[x1c], w11, v);
        res[k] = v;
    }

    const size_t obase = ((size_t)bc * HH + y) * WW + xpx;
    __builtin_nontemporal_store(res, reinterpret_cast<f32x4*>(warped + obase));

    // mask: x < 448; xpx multiple of 4, 448 % 4 == 0 -> quad-uniform
    const float mval = (xpx < (WW - BND)) ? 1.0f : 0.0f;
    f32x4 mv = { mval, mval, mval, mval };
    __builtin_nontemporal_store(mv, reinterpret_cast<f32x4*>(maskout + obase));
}

extern "C" void kernel_launch(void* const* d_in, const int* in_sizes, int n_in,
                              void* d_out, int out_size, void* d_ws, size_t ws_size,
                              hipStream_t stream) {
    const float* disp = (const float*)d_in[0];
    const float* tgt  = (const float*)d_in[1];
    float* warped  = (float*)d_out;
    float* maskout = (float*)d_out + (size_t)BB * CC * HH * WW;

    const int grid = BB * CC * (HH / 2);         // 65536
    hipLaunchKernelGGL(warp_feature_kernel, dim3(grid), dim3(256), 0, stream,
                       disp, tgt, warped, maskout);
}